// Round 1
// baseline (3586.392 us; speedup 1.0000x reference)
//
#include <hip/hip_runtime.h>

#define BB 32
#define NPTS0 2048
#define KNB 16

constexpr int ilog2c(int n){ int l=0; while(n>1){ n>>=1; ++l; } return l; }

static __device__ __forceinline__ float sq3(float a, float b, float c){
  return __fadd_rn(__fadd_rn(__fmul_rn(a,a),__fmul_rn(b,b)),__fmul_rn(c,c));
}

// ---------------- input projection: f0[b][n][o] = w_in(8x3) @ x + b_in ----------------
__global__ __launch_bounds__(256) void proj_kernel(const float* __restrict__ x,
    const float* __restrict__ w, const float* __restrict__ bias, float* __restrict__ f0)
{
  int gid = blockIdx.x*256 + threadIdx.x;
  if (gid >= BB*NPTS0) return;
  float x0 = x[gid*3+0], x1 = x[gid*3+1], x2 = x[gid*3+2];
  #pragma unroll
  for (int o = 0; o < 8; ++o){
    float acc = __fmul_rn(w[o*3+0], x0);
    acc = __fmaf_rn(w[o*3+1], x1, acc);
    acc = __fmaf_rn(w[o*3+2], x2, acc);
    f0[gid*8+o] = __fadd_rn(acc, bias[o]);
  }
}

// ---------------- kNN: top-16 smallest of d = (qq - 2*dot) + kk, ties -> lower index ----
__global__ __launch_bounds__(256) void knn_kernel(const float* __restrict__ qpts,
    const float* __restrict__ kpts, int Nq, int Nk, int* __restrict__ oidx)
{
  __shared__ float kx[2048], ky[2048], kz[2048], kq[2048];
  int b = blockIdx.x, tid = threadIdx.x;
  for (int j = tid; j < Nk; j += 256){
    float a = kpts[(b*Nk+j)*3+0];
    float c = kpts[(b*Nk+j)*3+1];
    float d = kpts[(b*Nk+j)*3+2];
    kx[j]=a; ky[j]=c; kz[j]=d;
    kq[j] = sq3(a,c,d);
  }
  __syncthreads();
  int q = blockIdx.y*256 + tid;
  if (q >= Nq) return;
  float qx = qpts[(b*Nq+q)*3+0], qy = qpts[(b*Nq+q)*3+1], qz = qpts[(b*Nq+q)*3+2];
  float qq = sq3(qx,qy,qz);
  float th[KNB]; int ti[KNB];
  #pragma unroll
  for (int i=0;i<KNB;i++){ th[i] = __builtin_inff(); ti[i] = 0; }
  for (int j=0;j<Nk;j++){
    float dot = __fmul_rn(qx,kx[j]);
    dot = __fmaf_rn(qy,ky[j],dot);
    dot = __fmaf_rn(qz,kz[j],dot);
    float d = __fadd_rn(__fsub_rn(qq, __fmul_rn(2.0f,dot)), kq[j]);
    if (d < th[KNB-1]){                   // strict <: equal dist keeps earlier index
      th[KNB-1] = d; ti[KNB-1] = j;
      #pragma unroll
      for (int i=KNB-1;i>0;--i){          // bubble up, static indices only
        if (th[i] < th[i-1]){
          float tv=th[i]; th[i]=th[i-1]; th[i-1]=tv;
          int tj=ti[i]; ti[i]=ti[i-1]; ti[i-1]=tj;
        }
      }
    }
  }
  #pragma unroll
  for (int i=0;i<KNB;i++) oidx[(b*Nq+q)*KNB + i] = ti[i];
}

// ---------------- per-point GEMV: out[pn][o] = sum_c M[o][c]*fin[pn][c] ----------------
// M = W[:, :C] (DIFF=false) or W[:, C:2C]-W[:, :C] (DIFF=true); W row stride = 2C.
template<int C, int O, bool DIFF>
__global__ __launch_bounds__(256) void gemv_kernel(const float* __restrict__ fin,
    const float* __restrict__ W, float* __restrict__ out, int Npts)
{
  constexpr int NT = O/8;
  constexpr int LNT = ilog2c(NT);
  int gid = blockIdx.x*256 + threadIdx.x;
  if (gid >= BB*Npts*NT) return;
  int tile = gid & (NT-1);
  int pn = gid >> LNT;
  const float* frow = fin + pn*C;
  float f[C];
  #pragma unroll
  for (int c=0;c<C;c++) f[c] = frow[c];
  float acc[8];
  const float* wbase = W + (tile*8)*(2*C);
  #pragma unroll
  for (int oo=0;oo<8;oo++){
    const float* wrow = wbase + oo*(2*C);
    float a = 0.f;
    #pragma unroll
    for (int c=0;c<C;c++){
      float wv = DIFF ? __fsub_rn(wrow[C+c], wrow[c]) : wrow[c];
      a = __fmaf_rn(wv, f[c], a);
    }
    acc[oo] = a;
  }
  float* orow = out + pn*O + tile*8;
  #pragma unroll
  for (int oo=0;oo<8;oo++) orow[oo] = acc[oo];
}

// ---------------- GN stats pass: per (b,group) partial sum/sumsq of y = A[idx]+B --------
template<int O>
__global__ __launch_bounds__(256) void stats_kernel(const float* __restrict__ A,
    const float* __restrict__ Bq, const int* __restrict__ idx, int Nq, int Nk,
    double* __restrict__ part)
{
  constexpr int O4 = O/4;
  constexpr int LO4 = ilog2c(O4);
  int b = blockIdx.x, g = blockIdx.y, split = blockIdx.z;
  int nsplit = gridDim.z;
  int qlen = Nq / nsplit;
  int q0 = split * qlen;
  int tid = threadIdx.x;
  int total = qlen * KNB * O4;
  double s1 = 0.0, s2 = 0.0;
  for (int s = tid; s < total; s += 256){
    int oin = s & (O4-1);
    int rest = s >> LO4;
    int kk = rest & (KNB-1);
    int q = q0 + (rest >> 4);
    int j = idx[(b*Nq+q)*KNB + kk];
    float y = A[(b*Nk+j)*O + g*O4 + oin] + Bq[(b*Nq+q)*O + g*O4 + oin];
    s1 += (double)y;
    s2 += (double)y * (double)y;
  }
  #pragma unroll
  for (int m=32;m>0;m>>=1){ s1 += __shfl_down(s1,m); s2 += __shfl_down(s2,m); }
  __shared__ double sh1[4], sh2[4];
  int lane = tid & 63, w = tid >> 6;
  if (lane == 0){ sh1[w]=s1; sh2[w]=s2; }
  __syncthreads();
  if (tid == 0){
    double t1 = (sh1[0]+sh1[1])+(sh1[2]+sh1[3]);
    double t2 = (sh2[0]+sh2[1])+(sh2[2]+sh2[3]);
    int pi = (b*4+g)*nsplit + split;
    part[pi*2] = t1; part[pi*2+1] = t2;
  }
}

__global__ __launch_bounds__(128) void statsred_kernel(const double* __restrict__ part,
    int nsplit, double cnt, float* __restrict__ stats)
{
  int t = threadIdx.x;
  if (t >= BB*4) return;
  double s1=0.0, s2=0.0;
  for (int i=0;i<nsplit;i++){ s1 += part[(t*nsplit+i)*2]; s2 += part[(t*nsplit+i)*2+1]; }
  double mean = s1/cnt;
  double var = s2/cnt - mean*mean;
  double rstd = 1.0 / sqrt(var + 1e-5);
  stats[t*2] = (float)mean;
  stats[t*2+1] = (float)rstd;
}

// ---------------- final pass: normalize, gamma/beta, leaky, max over 16 neighbors ------
template<int O>
__global__ __launch_bounds__(256) void final_kernel(const float* __restrict__ A,
    const float* __restrict__ Bq, const int* __restrict__ idx,
    const float* __restrict__ stats, const float* __restrict__ gamma,
    const float* __restrict__ beta, float* __restrict__ fout, int Nq, int Nk)
{
  constexpr int LO = ilog2c(O);
  constexpr int LO4 = ilog2c(O/4);
  int b = blockIdx.y;
  int t = blockIdx.x*256 + threadIdx.x;
  if (t >= Nq*O) return;
  int o = t & (O-1);
  int q = t >> LO;
  int g = o >> LO4;
  float mu   = stats[(b*4+g)*2];
  float rstd = stats[(b*4+g)*2+1];
  float gam = gamma[o], bet = beta[o];
  float bq = Bq[(b*Nq+q)*O + o];
  const int* ip = idx + (b*Nq+q)*KNB;
  float m = -__builtin_inff();
  #pragma unroll
  for (int kk=0;kk<KNB;kk++){
    int j = ip[kk];
    float y = A[(b*Nk+j)*O + o] + bq;
    float yn = __fmul_rn(__fsub_rn(y, mu), rstd);
    float yv = __fadd_rn(__fmul_rn(yn, gam), bet);
    float l = yv >= 0.f ? yv : 0.2f*yv;
    m = fmaxf(m, l);
  }
  fout[(b*Nq+q)*O + o] = m;
}

// ---------------- farthest point sampling (exact f32 ops, first-index argmax ties) -----
template<int NPT>   // points = NPT*256
__global__ __launch_bounds__(256) void fps_kernel(const float* __restrict__ pts,
    int S, int* __restrict__ oidx)
{
  constexpr int N = NPT*256;
  __shared__ float px[2048], py[2048], pz[2048];
  __shared__ float swv[2][4]; __shared__ int swi[2][4];
  int b = blockIdx.x, tid = threadIdx.x;
  for (int i = tid; i < N; i += 256){
    px[i] = pts[(b*N+i)*3+0];
    py[i] = pts[(b*N+i)*3+1];
    pz[i] = pts[(b*N+i)*3+2];
  }
  __syncthreads();
  float p0x = px[0], p0y = py[0], p0z = pz[0];
  float dist[NPT];
  #pragma unroll
  for (int t=0;t<NPT;t++){
    int i = t*256 + tid;
    float dx = __fsub_rn(px[i], p0x);
    float dy = __fsub_rn(py[i], p0y);
    float dz = __fsub_rn(pz[i], p0z);
    dist[t] = sq3(dx,dy,dz);
  }
  if (tid == 0) oidx[b*S+0] = 0;
  for (int s=1; s<S; ++s){
    float bv = dist[0]; int bi = tid;
    #pragma unroll
    for (int t=1;t<NPT;t++){
      int i = t*256 + tid;
      if (dist[t] > bv || (dist[t] == bv && i < bi)){ bv = dist[t]; bi = i; }
    }
    #pragma unroll
    for (int m=32;m>0;m>>=1){
      float ov = __shfl_xor(bv, m);
      int  oi = __shfl_xor(bi, m);
      if (ov > bv || (ov == bv && oi < bi)){ bv = ov; bi = oi; }
    }
    int par = s & 1;
    if ((tid & 63) == 0){ swv[par][tid>>6] = bv; swi[par][tid>>6] = bi; }
    __syncthreads();                          // single barrier per iteration (parity dbuf)
    float fv = swv[par][0]; int fi = swi[par][0];
    #pragma unroll
    for (int w=1;w<4;w++){
      float v = swv[par][w]; int ii = swi[par][w];
      if (v > fv || (v == fv && ii < fi)){ fv = v; fi = ii; }
    }
    if (tid == 0) oidx[b*S+s] = fi;
    float sx = px[fi], sy = py[fi], sz = pz[fi];
    #pragma unroll
    for (int t=0;t<NPT;t++){
      int i = t*256 + tid;
      float dx = __fsub_rn(px[i], sx);
      float dy = __fsub_rn(py[i], sy);
      float dz = __fsub_rn(pz[i], sz);
      float nd = sq3(dx,dy,dz);
      dist[t] = fminf(dist[t], nd);
    }
  }
}

// ---------------- gather coords + feats at fps indices --------------------------------
template<int C>
__global__ __launch_bounds__(256) void gather_kernel(const int* __restrict__ fidx,
    const float* __restrict__ pts, const float* __restrict__ fin,
    float* __restrict__ cq, float* __restrict__ fq, int Nin, int Nout)
{
  int gid = blockIdx.x*256 + threadIdx.x;
  if (gid >= BB*Nout) return;
  int b = gid / Nout;
  int i = gid - b*Nout;
  int src = fidx[b*Nout + i];
  #pragma unroll
  for (int c=0;c<3;c++) cq[gid*3+c] = pts[(b*Nin+src)*3+c];
  #pragma unroll
  for (int c=0;c<C;c++) fq[gid*C+c] = fin[(b*Nin+src)*C+c];
}

extern "C" void kernel_launch(void* const* d_in, const int* in_sizes, int n_in,
                              void* d_out, int out_size, void* d_ws, size_t ws_size,
                              hipStream_t stream)
{
  (void)in_sizes; (void)n_in; (void)out_size; (void)ws_size;
  const float* x    = (const float*)d_in[0];
  const float* w_in = (const float*)d_in[1];
  const float* b_in = (const float*)d_in[2];
  const float* w1 = (const float*)d_in[3];
  const float* g1 = (const float*)d_in[4];
  const float* be1= (const float*)d_in[5];
  const float* w2 = (const float*)d_in[6];
  const float* g2 = (const float*)d_in[7];
  const float* be2= (const float*)d_in[8];
  const float* w3 = (const float*)d_in[9];
  const float* g3 = (const float*)d_in[10];
  const float* be3= (const float*)d_in[11];
  const float* w4 = (const float*)d_in[12];
  const float* g4 = (const float*)d_in[13];
  const float* be4= (const float*)d_in[14];
  // num0=512, num1=128 are device scalars; fixed by setup_inputs, hardcoded for grid dims.

  float* out = (float*)d_out;
  float* coor_out = out;                    // (32,128,3)
  float* f_out = out + BB*128*3;            // (32,128,256)

  char* ws = (char*)d_ws;
  size_t off = 0;
  auto alloc = [&](size_t bytes)->void*{ void* p = ws + off; off += (bytes + 255) & ~(size_t)255; return p; };

  float* f0     = (float*)alloc((size_t)BB*2048*8*4);
  int*   idx1   = (int*)  alloc((size_t)BB*2048*16*4);
  float* A1     = (float*)alloc((size_t)BB*2048*32*4);
  float* B1     = (float*)alloc((size_t)BB*2048*32*4);
  float* f1     = (float*)alloc((size_t)BB*2048*32*4);
  double* part  = (double*)alloc((size_t)BB*4*8*2*8);
  float* statsv = (float*)alloc((size_t)BB*4*2*4);
  int*   fidx0  = (int*)  alloc((size_t)BB*512*4);
  float* coorq1 = (float*)alloc((size_t)BB*512*3*4);
  float* fq1    = (float*)alloc((size_t)BB*512*32*4);
  int*   idx2   = (int*)  alloc((size_t)BB*512*16*4);
  float* A2     = (float*)alloc((size_t)BB*2048*64*4);
  float* B2     = (float*)alloc((size_t)BB*512*64*4);
  float* f2     = (float*)alloc((size_t)BB*512*64*4);
  int*   idx3   = (int*)  alloc((size_t)BB*512*16*4);
  float* A3     = (float*)alloc((size_t)BB*512*64*4);
  float* B3     = (float*)alloc((size_t)BB*512*64*4);
  float* f3     = (float*)alloc((size_t)BB*512*64*4);
  int*   fidx1  = (int*)  alloc((size_t)BB*128*4);
  float* fq2    = (float*)alloc((size_t)BB*128*64*4);
  int*   idx4   = (int*)  alloc((size_t)BB*128*16*4);
  float* A4     = (float*)alloc((size_t)BB*512*256*4);
  float* B4     = (float*)alloc((size_t)BB*128*256*4);
  // total ~92 MB

  auto cdiv = [](int a, int b){ return (a+b-1)/b; };

  // stage 0: projection
  proj_kernel<<<cdiv(BB*2048,256),256,0,stream>>>(x, w_in, b_in, f0);

  // ---- stage 1: full 2048 pts ----
  knn_kernel<<<dim3(BB,8),256,0,stream>>>(x, x, 2048, 2048, idx1);
  gemv_kernel<8,32,false><<<cdiv(BB*2048*4,256),256,0,stream>>>(f0, w1, A1, 2048);
  gemv_kernel<8,32,true ><<<cdiv(BB*2048*4,256),256,0,stream>>>(f0, w1, B1, 2048);
  stats_kernel<32><<<dim3(BB,4,8),256,0,stream>>>(A1, B1, idx1, 2048, 2048, part);
  statsred_kernel<<<1,128,0,stream>>>(part, 8, 8.0*2048*16, statsv);
  final_kernel<32><<<dim3(cdiv(2048*32,256),BB),256,0,stream>>>(A1, B1, idx1, statsv, g1, be1, f1, 2048, 2048);

  // ---- fps 2048 -> 512 + gather ----
  fps_kernel<8><<<BB,256,0,stream>>>(x, 512, fidx0);
  gather_kernel<32><<<cdiv(BB*512,256),256,0,stream>>>(fidx0, x, f1, coorq1, fq1, 2048, 512);

  // ---- stage 2: queries 512, keys 2048 ----
  knn_kernel<<<dim3(BB,2),256,0,stream>>>(coorq1, x, 512, 2048, idx2);
  gemv_kernel<32,64,false><<<cdiv(BB*2048*8,256),256,0,stream>>>(f1, w2, A2, 2048);
  gemv_kernel<32,64,true ><<<cdiv(BB*512*8,256),256,0,stream>>>(fq1, w2, B2, 512);
  stats_kernel<64><<<dim3(BB,4,8),256,0,stream>>>(A2, B2, idx2, 512, 2048, part);
  statsred_kernel<<<1,128,0,stream>>>(part, 8, 16.0*512*16, statsv);
  final_kernel<64><<<dim3(cdiv(512*64,256),BB),256,0,stream>>>(A2, B2, idx2, statsv, g2, be2, f2, 512, 2048);

  // ---- stage 3: 512 x 512 ----
  knn_kernel<<<dim3(BB,2),256,0,stream>>>(coorq1, coorq1, 512, 512, idx3);
  gemv_kernel<64,64,false><<<cdiv(BB*512*8,256),256,0,stream>>>(f2, w3, A3, 512);
  gemv_kernel<64,64,true ><<<cdiv(BB*512*8,256),256,0,stream>>>(f2, w3, B3, 512);
  stats_kernel<64><<<dim3(BB,4,8),256,0,stream>>>(A3, B3, idx3, 512, 512, part);
  statsred_kernel<<<1,128,0,stream>>>(part, 8, 16.0*512*16, statsv);
  final_kernel<64><<<dim3(cdiv(512*64,256),BB),256,0,stream>>>(A3, B3, idx3, statsv, g3, be3, f3, 512, 512);

  // ---- fps 512 -> 128 + gather (coords straight into d_out) ----
  fps_kernel<2><<<BB,256,0,stream>>>(coorq1, 128, fidx1);
  gather_kernel<64><<<cdiv(BB*128,256),256,0,stream>>>(fidx1, coorq1, f3, coor_out, fq2, 512, 128);

  // ---- stage 4: queries 128, keys 512 ----
  knn_kernel<<<dim3(BB,1),256,0,stream>>>(coor_out, coorq1, 128, 512, idx4);
  gemv_kernel<64,256,false><<<cdiv(BB*512*32,256),256,0,stream>>>(f3, w4, A4, 512);
  gemv_kernel<64,256,true ><<<cdiv(BB*128*32,256),256,0,stream>>>(fq2, w4, B4, 128);
  stats_kernel<256><<<dim3(BB,4,8),256,0,stream>>>(A4, B4, idx4, 128, 512, part);
  statsred_kernel<<<1,128,0,stream>>>(part, 8, 64.0*128*16, statsv);
  final_kernel<256><<<dim3(cdiv(128*256,256),BB),256,0,stream>>>(A4, B4, idx4, statsv, g4, be4, f_out, 128, 512);
}

// Round 2
// 1979.500 us; speedup vs baseline: 1.8118x; 1.8118x over previous
//
#include <hip/hip_runtime.h>

#define BB 32
#define NPTS0 2048
#define KNB 16
#define KC 256   // key-chunk size for two-pass kNN

constexpr int ilog2c(int n){ int l=0; while(n>1){ n>>=1; ++l; } return l; }

static __device__ __forceinline__ float sq3(float a, float b, float c){
  return __fadd_rn(__fadd_rn(__fmul_rn(a,a),__fmul_rn(b,b)),__fmul_rn(c,c));
}

// ---------------- input projection: f0[b][n][o] = w_in(8x3) @ x + b_in ----------------
__global__ __launch_bounds__(256) void proj_kernel(const float* __restrict__ x,
    const float* __restrict__ w, const float* __restrict__ bias, float* __restrict__ f0)
{
  int gid = blockIdx.x*256 + threadIdx.x;
  if (gid >= BB*NPTS0) return;
  float x0 = x[gid*3+0], x1 = x[gid*3+1], x2 = x[gid*3+2];
  #pragma unroll
  for (int o = 0; o < 8; ++o){
    float acc = __fmul_rn(w[o*3+0], x0);
    acc = __fmaf_rn(w[o*3+1], x1, acc);
    acc = __fmaf_rn(w[o*3+2], x2, acc);
    f0[gid*8+o] = __fadd_rn(acc, bias[o]);
  }
}

// ---------------- kNN pass 1: per 256-key chunk, local top-16 ----------------
// grid (BB, qchunks, kchunks), block 256. Distances identical to full-scan version:
// d = (qq - 2*dot) + kq, strict-< insert => ties keep lower (local) index.
__global__ __launch_bounds__(256) void knn_part_kernel(const float* __restrict__ qpts,
    const float* __restrict__ kpts, int Nq, int Nk,
    float* __restrict__ pd, unsigned char* __restrict__ pi)
{
  __shared__ float4 kk4[KC];
  int b = blockIdx.x, tid = threadIdx.x;
  int kc = blockIdx.z, nkc = gridDim.z;
  {
    int j = kc*KC + tid;                 // Nk is always a multiple of 256
    float a = kpts[(b*Nk+j)*3+0];
    float c = kpts[(b*Nk+j)*3+1];
    float d = kpts[(b*Nk+j)*3+2];
    kk4[tid] = make_float4(a, c, d, sq3(a,c,d));
  }
  __syncthreads();
  int q = blockIdx.y*256 + tid;
  if (q >= Nq) return;
  float qx = qpts[(b*Nq+q)*3+0], qy = qpts[(b*Nq+q)*3+1], qz = qpts[(b*Nq+q)*3+2];
  float qq = sq3(qx,qy,qz);
  float th[KNB]; int ti[KNB];
  #pragma unroll
  for (int i=0;i<KNB;i++){ th[i] = __builtin_inff(); ti[i] = 0; }
  for (int j=0;j<KC;j++){
    float4 k4 = kk4[j];
    float dot = __fmul_rn(qx,k4.x);
    dot = __fmaf_rn(qy,k4.y,dot);
    dot = __fmaf_rn(qz,k4.z,dot);
    float d = __fadd_rn(__fsub_rn(qq, __fmul_rn(2.0f,dot)), k4.w);
    if (d < th[KNB-1]){                   // strict <: equal dist keeps earlier index
      th[KNB-1] = d; ti[KNB-1] = j;
      #pragma unroll
      for (int i=KNB-1;i>0;--i){          // bubble up, static indices only
        if (th[i] < th[i-1]){
          float tv=th[i]; th[i]=th[i-1]; th[i-1]=tv;
          int tj=ti[i]; ti[i]=ti[i-1]; ti[i-1]=tj;
        }
      }
    }
  }
  size_t base = ((size_t)(b*Nq+q)*nkc + kc)*KNB;
  #pragma unroll
  for (int i=0;i<KNB;i++){ pd[base+i] = th[i]; pi[base+i] = (unsigned char)ti[i]; }
}

// ---------------- kNN pass 2: merge per-chunk sorted candidate lists ----------------
// one thread per query; chunks in ascending order + strict-< insert => global
// tie semantics identical to a single ascending-index scan.
__global__ __launch_bounds__(256) void knn_merge_kernel(const float* __restrict__ pd,
    const unsigned char* __restrict__ pi, int Nq, int nkc, int* __restrict__ oidx)
{
  int gid = blockIdx.x*256 + threadIdx.x;
  if (gid >= BB*Nq) return;               // gid = b*Nq + q
  float th[KNB]; int ti[KNB];
  #pragma unroll
  for (int i=0;i<KNB;i++){ th[i] = __builtin_inff(); ti[i] = 0; }
  size_t base = (size_t)gid*nkc*KNB;
  for (int kc=0;kc<nkc;kc++){
    size_t cb = base + (size_t)kc*KNB;
    for (int i=0;i<KNB;i++){
      float d = pd[cb+i];
      if (d >= th[KNB-1]) break;           // chunk list sorted ascending
      int j = kc*KC + (int)pi[cb+i];
      th[KNB-1] = d; ti[KNB-1] = j;
      #pragma unroll
      for (int m=KNB-1;m>0;--m){
        if (th[m] < th[m-1]){
          float tv=th[m]; th[m]=th[m-1]; th[m-1]=tv;
          int tj=ti[m]; ti[m]=ti[m-1]; ti[m-1]=tj;
        }
      }
    }
  }
  #pragma unroll
  for (int i=0;i<KNB;i++) oidx[gid*KNB + i] = ti[i];
}

// ---------------- per-point GEMV: out[pn][o] = sum_c M[o][c]*fin[pn][c] ----------------
template<int C, int O, bool DIFF>
__global__ __launch_bounds__(256) void gemv_kernel(const float* __restrict__ fin,
    const float* __restrict__ W, float* __restrict__ out, int Npts)
{
  constexpr int NT = O/8;
  constexpr int LNT = ilog2c(NT);
  int gid = blockIdx.x*256 + threadIdx.x;
  if (gid >= BB*Npts*NT) return;
  int tile = gid & (NT-1);
  int pn = gid >> LNT;
  const float* frow = fin + pn*C;
  float f[C];
  #pragma unroll
  for (int c=0;c<C;c++) f[c] = frow[c];
  float acc[8];
  const float* wbase = W + (tile*8)*(2*C);
  #pragma unroll
  for (int oo=0;oo<8;oo++){
    const float* wrow = wbase + oo*(2*C);
    float a = 0.f;
    #pragma unroll
    for (int c=0;c<C;c++){
      float wv = DIFF ? __fsub_rn(wrow[C+c], wrow[c]) : wrow[c];
      a = __fmaf_rn(wv, f[c], a);
    }
    acc[oo] = a;
  }
  float* orow = out + pn*O + tile*8;
  #pragma unroll
  for (int oo=0;oo<8;oo++) orow[oo] = acc[oo];
}

// ---------------- GN stats pass: per (b,group) partial sum/sumsq of y = A[idx]+B --------
template<int O>
__global__ __launch_bounds__(256) void stats_kernel(const float* __restrict__ A,
    const float* __restrict__ Bq, const int* __restrict__ idx, int Nq, int Nk,
    double* __restrict__ part)
{
  constexpr int O4 = O/4;
  constexpr int LO4 = ilog2c(O4);
  int b = blockIdx.x, g = blockIdx.y, split = blockIdx.z;
  int nsplit = gridDim.z;
  int qlen = Nq / nsplit;
  int q0 = split * qlen;
  int tid = threadIdx.x;
  int total = qlen * KNB * O4;
  double s1 = 0.0, s2 = 0.0;
  for (int s = tid; s < total; s += 256){
    int oin = s & (O4-1);
    int rest = s >> LO4;
    int kk = rest & (KNB-1);
    int q = q0 + (rest >> 4);
    int j = idx[(b*Nq+q)*KNB + kk];
    float y = A[(b*Nk+j)*O + g*O4 + oin] + Bq[(b*Nq+q)*O + g*O4 + oin];
    s1 += (double)y;
    s2 += (double)y * (double)y;
  }
  #pragma unroll
  for (int m=32;m>0;m>>=1){ s1 += __shfl_down(s1,m); s2 += __shfl_down(s2,m); }
  __shared__ double sh1[4], sh2[4];
  int lane = tid & 63, w = tid >> 6;
  if (lane == 0){ sh1[w]=s1; sh2[w]=s2; }
  __syncthreads();
  if (tid == 0){
    double t1 = (sh1[0]+sh1[1])+(sh1[2]+sh1[3]);
    double t2 = (sh2[0]+sh2[1])+(sh2[2]+sh2[3]);
    int pi = (b*4+g)*nsplit + split;
    part[pi*2] = t1; part[pi*2+1] = t2;
  }
}

__global__ __launch_bounds__(128) void statsred_kernel(const double* __restrict__ part,
    int nsplit, double cnt, float* __restrict__ stats)
{
  int t = threadIdx.x;
  if (t >= BB*4) return;
  double s1=0.0, s2=0.0;
  for (int i=0;i<nsplit;i++){ s1 += part[(t*nsplit+i)*2]; s2 += part[(t*nsplit+i)*2+1]; }
  double mean = s1/cnt;
  double var = s2/cnt - mean*mean;
  double rstd = 1.0 / sqrt(var + 1e-5);
  stats[t*2] = (float)mean;
  stats[t*2+1] = (float)rstd;
}

// ---------------- final pass: normalize, gamma/beta, leaky, max over 16 neighbors ------
template<int O>
__global__ __launch_bounds__(256) void final_kernel(const float* __restrict__ A,
    const float* __restrict__ Bq, const int* __restrict__ idx,
    const float* __restrict__ stats, const float* __restrict__ gamma,
    const float* __restrict__ beta, float* __restrict__ fout, int Nq, int Nk)
{
  constexpr int LO = ilog2c(O);
  constexpr int LO4 = ilog2c(O/4);
  int b = blockIdx.y;
  int t = blockIdx.x*256 + threadIdx.x;
  if (t >= Nq*O) return;
  int o = t & (O-1);
  int q = t >> LO;
  int g = o >> LO4;
  float mu   = stats[(b*4+g)*2];
  float rstd = stats[(b*4+g)*2+1];
  float gam = gamma[o], bet = beta[o];
  float bq = Bq[(b*Nq+q)*O + o];
  const int* ip = idx + (b*Nq+q)*KNB;
  float m = -__builtin_inff();
  #pragma unroll
  for (int kk=0;kk<KNB;kk++){
    int j = ip[kk];
    float y = A[(b*Nk+j)*O + o] + bq;
    float yn = __fmul_rn(__fsub_rn(y, mu), rstd);
    float yv = __fadd_rn(__fmul_rn(yn, gam), bet);
    float l = yv >= 0.f ? yv : 0.2f*yv;
    m = fmaxf(m, l);
  }
  fout[(b*Nq+q)*O + o] = m;
}

// ---------------- farthest point sampling (exact f32 ops, first-index argmax ties) -----
template<int NPT>   // points = NPT*256
__global__ __launch_bounds__(256) void fps_kernel(const float* __restrict__ pts,
    int S, int* __restrict__ oidx)
{
  constexpr int N = NPT*256;
  __shared__ float px[2048], py[2048], pz[2048];
  __shared__ float swv[2][4]; __shared__ int swi[2][4];
  int b = blockIdx.x, tid = threadIdx.x;
  for (int i = tid; i < N; i += 256){
    px[i] = pts[(b*N+i)*3+0];
    py[i] = pts[(b*N+i)*3+1];
    pz[i] = pts[(b*N+i)*3+2];
  }
  __syncthreads();
  float p0x = px[0], p0y = py[0], p0z = pz[0];
  float dist[NPT];
  #pragma unroll
  for (int t=0;t<NPT;t++){
    int i = t*256 + tid;
    float dx = __fsub_rn(px[i], p0x);
    float dy = __fsub_rn(py[i], p0y);
    float dz = __fsub_rn(pz[i], p0z);
    dist[t] = sq3(dx,dy,dz);
  }
  if (tid == 0) oidx[b*S+0] = 0;
  for (int s=1; s<S; ++s){
    float bv = dist[0]; int bi = tid;
    #pragma unroll
    for (int t=1;t<NPT;t++){
      int i = t*256 + tid;
      if (dist[t] > bv || (dist[t] == bv && i < bi)){ bv = dist[t]; bi = i; }
    }
    #pragma unroll
    for (int m=32;m>0;m>>=1){
      float ov = __shfl_xor(bv, m);
      int  oi = __shfl_xor(bi, m);
      if (ov > bv || (ov == bv && oi < bi)){ bv = ov; bi = oi; }
    }
    int par = s & 1;
    if ((tid & 63) == 0){ swv[par][tid>>6] = bv; swi[par][tid>>6] = bi; }
    __syncthreads();                          // single barrier per iteration (parity dbuf)
    float fv = swv[par][0]; int fi = swi[par][0];
    #pragma unroll
    for (int w=1;w<4;w++){
      float v = swv[par][w]; int ii = swi[par][w];
      if (v > fv || (v == fv && ii < fi)){ fv = v; fi = ii; }
    }
    if (tid == 0) oidx[b*S+s] = fi;
    float sx = px[fi], sy = py[fi], sz = pz[fi];
    #pragma unroll
    for (int t=0;t<NPT;t++){
      int i = t*256 + tid;
      float dx = __fsub_rn(px[i], sx);
      float dy = __fsub_rn(py[i], sy);
      float dz = __fsub_rn(pz[i], sz);
      float nd = sq3(dx,dy,dz);
      dist[t] = fminf(dist[t], nd);
    }
  }
}

// ---------------- gather coords + feats at fps indices --------------------------------
template<int C>
__global__ __launch_bounds__(256) void gather_kernel(const int* __restrict__ fidx,
    const float* __restrict__ pts, const float* __restrict__ fin,
    float* __restrict__ cq, float* __restrict__ fq, int Nin, int Nout)
{
  int gid = blockIdx.x*256 + threadIdx.x;
  if (gid >= BB*Nout) return;
  int b = gid / Nout;
  int i = gid - b*Nout;
  int src = fidx[b*Nout + i];
  #pragma unroll
  for (int c=0;c<3;c++) cq[gid*3+c] = pts[(b*Nin+src)*3+c];
  #pragma unroll
  for (int c=0;c<C;c++) fq[gid*C+c] = fin[(b*Nin+src)*C+c];
}

extern "C" void kernel_launch(void* const* d_in, const int* in_sizes, int n_in,
                              void* d_out, int out_size, void* d_ws, size_t ws_size,
                              hipStream_t stream)
{
  (void)in_sizes; (void)n_in; (void)out_size; (void)ws_size;
  const float* x    = (const float*)d_in[0];
  const float* w_in = (const float*)d_in[1];
  const float* b_in = (const float*)d_in[2];
  const float* w1 = (const float*)d_in[3];
  const float* g1 = (const float*)d_in[4];
  const float* be1= (const float*)d_in[5];
  const float* w2 = (const float*)d_in[6];
  const float* g2 = (const float*)d_in[7];
  const float* be2= (const float*)d_in[8];
  const float* w3 = (const float*)d_in[9];
  const float* g3 = (const float*)d_in[10];
  const float* be3= (const float*)d_in[11];
  const float* w4 = (const float*)d_in[12];
  const float* g4 = (const float*)d_in[13];
  const float* be4= (const float*)d_in[14];

  float* out = (float*)d_out;
  float* coor_out = out;                    // (32,128,3)
  float* f_out = out + BB*128*3;            // (32,128,256)

  char* ws = (char*)d_ws;
  size_t off = 0;
  auto alloc = [&](size_t bytes)->void*{ void* p = ws + off; off += (bytes + 255) & ~(size_t)255; return p; };

  // ---- persistent buffers (~28 MB) ----
  float* f0     = (float*)alloc((size_t)BB*2048*8*4);
  int*   idx1   = (int*)  alloc((size_t)BB*2048*16*4);
  float* f1     = (float*)alloc((size_t)BB*2048*32*4);
  double* part  = (double*)alloc((size_t)BB*4*8*2*8);
  float* statsv = (float*)alloc((size_t)BB*4*2*4);
  int*   fidx0  = (int*)  alloc((size_t)BB*512*4);
  float* coorq1 = (float*)alloc((size_t)BB*512*3*4);
  float* fq1    = (float*)alloc((size_t)BB*512*32*4);
  int*   idx2   = (int*)  alloc((size_t)BB*512*16*4);
  float* f2     = (float*)alloc((size_t)BB*512*64*4);
  int*   idx3   = (int*)  alloc((size_t)BB*512*16*4);
  float* f3     = (float*)alloc((size_t)BB*512*64*4);
  int*   fidx1  = (int*)  alloc((size_t)BB*128*4);
  float* fq2    = (float*)alloc((size_t)BB*128*64*4);
  int*   idx4   = (int*)  alloc((size_t)BB*128*16*4);

  // ---- union scratch region (48 MB): kNN partials alias the A/B edge-conv buffers.
  // Lifetimes per stage: knn_part/merge use (pd,pi); then gemv/stats/final use (A,B).
  char* U = (char*)alloc((size_t)48<<20);
  float* pd         = (float*)U;                          // max 32*2048*8*16*4 = 32 MiB
  unsigned char* pi = (unsigned char*)(U + ((size_t)34<<20)); // max 8 MiB
  float* A  = (float*)U;                                  // max 32*2048*64*4 = 16 MiB
  float* Bq = (float*)(U + ((size_t)20<<20));             // max 4 MiB

  auto cdiv = [](int a, int b){ return (a+b-1)/b; };

  // stage 0: projection
  proj_kernel<<<cdiv(BB*2048,256),256,0,stream>>>(x, w_in, b_in, f0);

  // ---- stage 1: 2048 q x 2048 k ----
  knn_part_kernel<<<dim3(BB,8,8),256,0,stream>>>(x, x, 2048, 2048, pd, pi);
  knn_merge_kernel<<<cdiv(BB*2048,256),256,0,stream>>>(pd, pi, 2048, 8, idx1);
  gemv_kernel<8,32,false><<<cdiv(BB*2048*4,256),256,0,stream>>>(f0, w1, A, 2048);
  gemv_kernel<8,32,true ><<<cdiv(BB*2048*4,256),256,0,stream>>>(f0, w1, Bq, 2048);
  stats_kernel<32><<<dim3(BB,4,8),256,0,stream>>>(A, Bq, idx1, 2048, 2048, part);
  statsred_kernel<<<1,128,0,stream>>>(part, 8, 8.0*2048*16, statsv);
  final_kernel<32><<<dim3(cdiv(2048*32,256),BB),256,0,stream>>>(A, Bq, idx1, statsv, g1, be1, f1, 2048, 2048);

  // ---- fps 2048 -> 512 + gather ----
  fps_kernel<8><<<BB,256,0,stream>>>(x, 512, fidx0);
  gather_kernel<32><<<cdiv(BB*512,256),256,0,stream>>>(fidx0, x, f1, coorq1, fq1, 2048, 512);

  // ---- stage 2: 512 q x 2048 k ----
  knn_part_kernel<<<dim3(BB,2,8),256,0,stream>>>(coorq1, x, 512, 2048, pd, pi);
  knn_merge_kernel<<<cdiv(BB*512,256),256,0,stream>>>(pd, pi, 512, 8, idx2);
  gemv_kernel<32,64,false><<<cdiv(BB*2048*8,256),256,0,stream>>>(f1, w2, A, 2048);
  gemv_kernel<32,64,true ><<<cdiv(BB*512*8,256),256,0,stream>>>(fq1, w2, Bq, 512);
  stats_kernel<64><<<dim3(BB,4,8),256,0,stream>>>(A, Bq, idx2, 512, 2048, part);
  statsred_kernel<<<1,128,0,stream>>>(part, 8, 16.0*512*16, statsv);
  final_kernel<64><<<dim3(cdiv(512*64,256),BB),256,0,stream>>>(A, Bq, idx2, statsv, g2, be2, f2, 512, 2048);

  // ---- stage 3: 512 q x 512 k ----
  knn_part_kernel<<<dim3(BB,2,2),256,0,stream>>>(coorq1, coorq1, 512, 512, pd, pi);
  knn_merge_kernel<<<cdiv(BB*512,256),256,0,stream>>>(pd, pi, 512, 2, idx3);
  gemv_kernel<64,64,false><<<cdiv(BB*512*8,256),256,0,stream>>>(f2, w3, A, 512);
  gemv_kernel<64,64,true ><<<cdiv(BB*512*8,256),256,0,stream>>>(f2, w3, Bq, 512);
  stats_kernel<64><<<dim3(BB,4,8),256,0,stream>>>(A, Bq, idx3, 512, 512, part);
  statsred_kernel<<<1,128,0,stream>>>(part, 8, 16.0*512*16, statsv);
  final_kernel<64><<<dim3(cdiv(512*64,256),BB),256,0,stream>>>(A, Bq, idx3, statsv, g3, be3, f3, 512, 512);

  // ---- fps 512 -> 128 + gather (coords straight into d_out) ----
  fps_kernel<2><<<BB,256,0,stream>>>(coorq1, 128, fidx1);
  gather_kernel<64><<<cdiv(BB*128,256),256,0,stream>>>(fidx1, coorq1, f3, coor_out, fq2, 512, 128);

  // ---- stage 4: 128 q x 512 k ----
  knn_part_kernel<<<dim3(BB,1,2),256,0,stream>>>(coor_out, coorq1, 128, 512, pd, pi);
  knn_merge_kernel<<<cdiv(BB*128,256),256,0,stream>>>(pd, pi, 128, 2, idx4);
  gemv_kernel<64,256,false><<<cdiv(BB*512*32,256),256,0,stream>>>(f3, w4, A, 512);
  gemv_kernel<64,256,true ><<<cdiv(BB*128*32,256),256,0,stream>>>(fq2, w4, Bq, 128);
  stats_kernel<256><<<dim3(BB,4,8),256,0,stream>>>(A, Bq, idx4, 128, 512, part);
  statsred_kernel<<<1,128,0,stream>>>(part, 8, 64.0*128*16, statsv);
  final_kernel<256><<<dim3(cdiv(128*256,256),BB),256,0,stream>>>(A, Bq, idx4, statsv, g4, be4, f_out, 128, 512);
}

// Round 3
// 1592.564 us; speedup vs baseline: 2.2520x; 1.2430x over previous
//
#include <hip/hip_runtime.h>

#define BB 32
#define NPTS0 2048
#define KNB 16
#define KC 256   // key-chunk size for two-pass kNN

constexpr int ilog2c(int n){ int l=0; while(n>1){ n>>=1; ++l; } return l; }

static __device__ __forceinline__ float sq3(float a, float b, float c){
  return __fadd_rn(__fadd_rn(__fmul_rn(a,a),__fmul_rn(b,b)),__fmul_rn(c,c));
}

// ---------------- input projection: f0[b][n][o] = w_in(8x3) @ x + b_in ----------------
__global__ __launch_bounds__(256) void proj_kernel(const float* __restrict__ x,
    const float* __restrict__ w, const float* __restrict__ bias, float* __restrict__ f0)
{
  int gid = blockIdx.x*256 + threadIdx.x;
  if (gid >= BB*NPTS0) return;
  float x0 = x[gid*3+0], x1 = x[gid*3+1], x2 = x[gid*3+2];
  #pragma unroll
  for (int o = 0; o < 8; ++o){
    float acc = __fmul_rn(w[o*3+0], x0);
    acc = __fmaf_rn(w[o*3+1], x1, acc);
    acc = __fmaf_rn(w[o*3+2], x2, acc);
    f0[gid*8+o] = __fadd_rn(acc, bias[o]);
  }
}

// ---------------- kNN pass 1: per 256-key chunk, local top-16 ----------------
__global__ __launch_bounds__(256) void knn_part_kernel(const float* __restrict__ qpts,
    const float* __restrict__ kpts, int Nq, int Nk,
    float* __restrict__ pd, unsigned char* __restrict__ pi)
{
  __shared__ float4 kk4[KC];
  int b = blockIdx.x, tid = threadIdx.x;
  int kc = blockIdx.z, nkc = gridDim.z;
  {
    int j = kc*KC + tid;                 // Nk is always a multiple of 256
    float a = kpts[(b*Nk+j)*3+0];
    float c = kpts[(b*Nk+j)*3+1];
    float d = kpts[(b*Nk+j)*3+2];
    kk4[tid] = make_float4(a, c, d, sq3(a,c,d));
  }
  __syncthreads();
  int q = blockIdx.y*256 + tid;
  if (q >= Nq) return;
  float qx = qpts[(b*Nq+q)*3+0], qy = qpts[(b*Nq+q)*3+1], qz = qpts[(b*Nq+q)*3+2];
  float qq = sq3(qx,qy,qz);
  float th[KNB]; int ti[KNB];
  #pragma unroll
  for (int i=0;i<KNB;i++){ th[i] = __builtin_inff(); ti[i] = 0; }
  for (int j=0;j<KC;j++){
    float4 k4 = kk4[j];
    float dot = __fmul_rn(qx,k4.x);
    dot = __fmaf_rn(qy,k4.y,dot);
    dot = __fmaf_rn(qz,k4.z,dot);
    float d = __fadd_rn(__fsub_rn(qq, __fmul_rn(2.0f,dot)), k4.w);
    if (d < th[KNB-1]){                   // strict <: equal dist keeps earlier index
      th[KNB-1] = d; ti[KNB-1] = j;
      #pragma unroll
      for (int i=KNB-1;i>0;--i){
        if (th[i] < th[i-1]){
          float tv=th[i]; th[i]=th[i-1]; th[i-1]=tv;
          int tj=ti[i]; ti[i]=ti[i-1]; ti[i-1]=tj;
        }
      }
    }
  }
  size_t base = ((size_t)(b*Nq+q)*nkc + kc)*KNB;
  #pragma unroll
  for (int i=0;i<KNB;i++){ pd[base+i] = th[i]; pi[base+i] = (unsigned char)ti[i]; }
}

// ---------------- kNN pass 2: merge per-chunk sorted candidate lists ----------------
__global__ __launch_bounds__(256) void knn_merge_kernel(const float* __restrict__ pd,
    const unsigned char* __restrict__ pi, int Nq, int nkc, int* __restrict__ oidx)
{
  int gid = blockIdx.x*256 + threadIdx.x;
  if (gid >= BB*Nq) return;               // gid = b*Nq + q
  float th[KNB]; int ti[KNB];
  #pragma unroll
  for (int i=0;i<KNB;i++){ th[i] = __builtin_inff(); ti[i] = 0; }
  size_t base = (size_t)gid*nkc*KNB;
  for (int kc=0;kc<nkc;kc++){
    size_t cb = base + (size_t)kc*KNB;
    for (int i=0;i<KNB;i++){
      float d = pd[cb+i];
      if (d >= th[KNB-1]) break;           // chunk list sorted ascending
      int j = kc*KC + (int)pi[cb+i];
      th[KNB-1] = d; ti[KNB-1] = j;
      #pragma unroll
      for (int m=KNB-1;m>0;--m){
        if (th[m] < th[m-1]){
          float tv=th[m]; th[m]=th[m-1]; th[m-1]=tv;
          int tj=ti[m]; ti[m]=ti[m-1]; ti[m-1]=tj;
        }
      }
    }
  }
  #pragma unroll
  for (int i=0;i<KNB;i++) oidx[gid*KNB + i] = ti[i];
}

// ---------------- per-point GEMV: out[pn][o] = sum_c M[o][c]*fin[pn][c] ----------------
template<int C, int O, bool DIFF>
__global__ __launch_bounds__(256) void gemv_kernel(const float* __restrict__ fin,
    const float* __restrict__ W, float* __restrict__ out, int Npts)
{
  constexpr int NT = O/8;
  constexpr int LNT = ilog2c(NT);
  int gid = blockIdx.x*256 + threadIdx.x;
  if (gid >= BB*Npts*NT) return;
  int tile = gid & (NT-1);
  int pn = gid >> LNT;
  const float* frow = fin + pn*C;
  float f[C];
  #pragma unroll
  for (int c=0;c<C;c++) f[c] = frow[c];
  float acc[8];
  const float* wbase = W + (tile*8)*(2*C);
  #pragma unroll
  for (int oo=0;oo<8;oo++){
    const float* wrow = wbase + oo*(2*C);
    float a = 0.f;
    #pragma unroll
    for (int c=0;c<C;c++){
      float wv = DIFF ? __fsub_rn(wrow[C+c], wrow[c]) : wrow[c];
      a = __fmaf_rn(wv, f[c], a);
    }
    acc[oo] = a;
  }
  float* orow = out + pn*O + tile*8;
  #pragma unroll
  for (int oo=0;oo<8;oo++) orow[oo] = acc[oo];
}

// ---------------- GN stats pass: per (b,group) partial sum/sumsq of y = A[idx]+B --------
template<int O>
__global__ __launch_bounds__(256) void stats_kernel(const float* __restrict__ A,
    const float* __restrict__ Bq, const int* __restrict__ idx, int Nq, int Nk,
    double* __restrict__ part)
{
  constexpr int O4 = O/4;
  constexpr int LO4 = ilog2c(O4);
  int b = blockIdx.x, g = blockIdx.y, split = blockIdx.z;
  int nsplit = gridDim.z;
  int qlen = Nq / nsplit;
  int q0 = split * qlen;
  int tid = threadIdx.x;
  int total = qlen * KNB * O4;
  double s1 = 0.0, s2 = 0.0;
  for (int s = tid; s < total; s += 256){
    int oin = s & (O4-1);
    int rest = s >> LO4;
    int kk = rest & (KNB-1);
    int q = q0 + (rest >> 4);
    int j = idx[(b*Nq+q)*KNB + kk];
    float y = A[(b*Nk+j)*O + g*O4 + oin] + Bq[(b*Nq+q)*O + g*O4 + oin];
    s1 += (double)y;
    s2 += (double)y * (double)y;
  }
  #pragma unroll
  for (int m=32;m>0;m>>=1){ s1 += __shfl_down(s1,m); s2 += __shfl_down(s2,m); }
  __shared__ double sh1[4], sh2[4];
  int lane = tid & 63, w = tid >> 6;
  if (lane == 0){ sh1[w]=s1; sh2[w]=s2; }
  __syncthreads();
  if (tid == 0){
    double t1 = (sh1[0]+sh1[1])+(sh1[2]+sh1[3]);
    double t2 = (sh2[0]+sh2[1])+(sh2[2]+sh2[3]);
    int pi = (b*4+g)*nsplit + split;
    part[pi*2] = t1; part[pi*2+1] = t2;
  }
}

__global__ __launch_bounds__(128) void statsred_kernel(const double* __restrict__ part,
    int nsplit, double cnt, float* __restrict__ stats)
{
  int t = threadIdx.x;
  if (t >= BB*4) return;
  double s1=0.0, s2=0.0;
  for (int i=0;i<nsplit;i++){ s1 += part[(t*nsplit+i)*2]; s2 += part[(t*nsplit+i)*2+1]; }
  double mean = s1/cnt;
  double var = s2/cnt - mean*mean;
  double rstd = 1.0 / sqrt(var + 1e-5);
  stats[t*2] = (float)mean;
  stats[t*2+1] = (float)rstd;
}

// ---------------- final pass: normalize, gamma/beta, leaky, max over 16 neighbors ------
template<int O>
__global__ __launch_bounds__(256) void final_kernel(const float* __restrict__ A,
    const float* __restrict__ Bq, const int* __restrict__ idx,
    const float* __restrict__ stats, const float* __restrict__ gamma,
    const float* __restrict__ beta, float* __restrict__ fout, int Nq, int Nk)
{
  constexpr int LO = ilog2c(O);
  constexpr int LO4 = ilog2c(O/4);
  int b = blockIdx.y;
  int t = blockIdx.x*256 + threadIdx.x;
  if (t >= Nq*O) return;
  int o = t & (O-1);
  int q = t >> LO;
  int g = o >> LO4;
  float mu   = stats[(b*4+g)*2];
  float rstd = stats[(b*4+g)*2+1];
  float gam = gamma[o], bet = beta[o];
  float bq = Bq[(b*Nq+q)*O + o];
  const int* ip = idx + (b*Nq+q)*KNB;
  float m = -__builtin_inff();
  #pragma unroll
  for (int kk=0;kk<KNB;kk++){
    int j = ip[kk];
    float y = A[(b*Nk+j)*O + o] + bq;
    float yn = __fmul_rn(__fsub_rn(y, mu), rstd);
    float yv = __fadd_rn(__fmul_rn(yn, gam), bet);
    float l = yv >= 0.f ? yv : 0.2f*yv;
    m = fmaxf(m, l);
  }
  fout[(b*Nq+q)*O + o] = m;
}

// ---------------- farthest point sampling ------------------------------------------
// Packed-key argmax: key = (float_bits(dist) << 32) | ~idx. dist >= 0 so float bits
// are monotonic; max key = max dist with ties to LOWEST index (jnp.argmax semantics).
// Keys are unique (distinct idx) and always > 0, so the DPP bound_ctrl identity (0)
// can never win. Wave reduce via DPP (register file, no LDS round-trips).
#define FPS_DPPMAX(CTRL, RM) { \
  unsigned slo = (unsigned)__builtin_amdgcn_update_dpp((int)blo,(int)blo, CTRL, RM, 0xF, true); \
  unsigned shi = (unsigned)__builtin_amdgcn_update_dpp((int)bhi,(int)bhi, CTRL, RM, 0xF, true); \
  unsigned long long a_ = ((unsigned long long)bhi<<32)|blo; \
  unsigned long long q_ = ((unsigned long long)shi<<32)|slo; \
  if (q_ > a_){ blo=slo; bhi=shi; } }

template<int NPT>   // points = NPT*256
__global__ __launch_bounds__(256) void fps_kernel(const float* __restrict__ pts,
    int S, int* __restrict__ oidx)
{
  constexpr int N = NPT*256;
  __shared__ float4 p4[N];
  __shared__ __align__(16) unsigned long long swk[2][4];
  int b = blockIdx.x, tid = threadIdx.x;
  for (int i = tid; i < N; i += 256){
    float a = pts[(b*N+i)*3+0];
    float c = pts[(b*N+i)*3+1];
    float d = pts[(b*N+i)*3+2];
    p4[i] = make_float4(a, c, d, 0.f);
  }
  __syncthreads();
  float4 c0 = p4[0];
  float dist[NPT];
  unsigned nlo[NPT];
  unsigned blo, bhi;                      // running best packed key (this thread)
  {
    unsigned long long bk = 0ull;
    #pragma unroll
    for (int t=0;t<NPT;t++){
      int i = t*256 + tid;
      nlo[t] = ~(unsigned)i;
      float4 c = p4[i];
      float dx = __fsub_rn(c.x, c0.x);
      float dy = __fsub_rn(c.y, c0.y);
      float dz = __fsub_rn(c.z, c0.z);
      float d = sq3(dx,dy,dz);
      dist[t] = d;
      unsigned long long k = ((unsigned long long)__float_as_uint(d)<<32) | nlo[t];
      if (k > bk) bk = k;
    }
    blo = (unsigned)bk; bhi = (unsigned)(bk>>32);
  }
  if (tid == 0) oidx[b*S+0] = 0;
  for (int s=1; s<S; ++s){
    // ---- wave-level DPP max-reduce -> lane 63 ----
    FPS_DPPMAX(0x111, 0xF)   // row_shr:1
    FPS_DPPMAX(0x112, 0xF)   // row_shr:2
    FPS_DPPMAX(0x114, 0xF)   // row_shr:4
    FPS_DPPMAX(0x118, 0xF)   // row_shr:8  -> lane15 of each row has row max
    FPS_DPPMAX(0x142, 0xA)   // row_bcast:15 into rows 1,3
    FPS_DPPMAX(0x143, 0xC)   // row_bcast:31 into rows 2,3 -> lane63 global
    unsigned wlo = (unsigned)__builtin_amdgcn_readlane((int)blo, 63);
    unsigned whi = (unsigned)__builtin_amdgcn_readlane((int)bhi, 63);
    int par = s & 1;
    if ((tid & 63) == 0)
      swk[par][tid>>6] = ((unsigned long long)whi<<32) | wlo;
    __syncthreads();                      // single barrier per iteration (parity dbuf)
    ulonglong2 P0 = *reinterpret_cast<const ulonglong2*>(&swk[par][0]);
    ulonglong2 P1 = *reinterpret_cast<const ulonglong2*>(&swk[par][2]);
    unsigned long long m = P0.x;
    if (P0.y > m) m = P0.y;
    if (P1.x > m) m = P1.x;
    if (P1.y > m) m = P1.y;
    int fi = (int)(~(unsigned)m);         // recover index from key low word
    if (tid == 0) oidx[b*S+s] = fi;
    float4 cs = p4[fi];                   // broadcast read
    // ---- fused distance update + next-iteration local argmax ----
    unsigned long long bk = 0ull;
    #pragma unroll
    for (int t=0;t<NPT;t++){
      int i = t*256 + tid;
      float4 c = p4[i];
      float dx = __fsub_rn(c.x, cs.x);
      float dy = __fsub_rn(c.y, cs.y);
      float dz = __fsub_rn(c.z, cs.z);
      float nd = sq3(dx,dy,dz);
      float d = fminf(dist[t], nd);
      dist[t] = d;
      unsigned long long k = ((unsigned long long)__float_as_uint(d)<<32) | nlo[t];
      if (k > bk) bk = k;
    }
    blo = (unsigned)bk; bhi = (unsigned)(bk>>32);
  }
}

// ---------------- gather coords + feats at fps indices --------------------------------
template<int C>
__global__ __launch_bounds__(256) void gather_kernel(const int* __restrict__ fidx,
    const float* __restrict__ pts, const float* __restrict__ fin,
    float* __restrict__ cq, float* __restrict__ fq, int Nin, int Nout)
{
  int gid = blockIdx.x*256 + threadIdx.x;
  if (gid >= BB*Nout) return;
  int b = gid / Nout;
  int i = gid - b*Nout;
  int src = fidx[b*Nout + i];
  #pragma unroll
  for (int c=0;c<3;c++) cq[gid*3+c] = pts[(b*Nin+src)*3+c];
  #pragma unroll
  for (int c=0;c<C;c++) fq[gid*C+c] = fin[(b*Nin+src)*C+c];
}

extern "C" void kernel_launch(void* const* d_in, const int* in_sizes, int n_in,
                              void* d_out, int out_size, void* d_ws, size_t ws_size,
                              hipStream_t stream)
{
  (void)in_sizes; (void)n_in; (void)out_size; (void)ws_size;
  const float* x    = (const float*)d_in[0];
  const float* w_in = (const float*)d_in[1];
  const float* b_in = (const float*)d_in[2];
  const float* w1 = (const float*)d_in[3];
  const float* g1 = (const float*)d_in[4];
  const float* be1= (const float*)d_in[5];
  const float* w2 = (const float*)d_in[6];
  const float* g2 = (const float*)d_in[7];
  const float* be2= (const float*)d_in[8];
  const float* w3 = (const float*)d_in[9];
  const float* g3 = (const float*)d_in[10];
  const float* be3= (const float*)d_in[11];
  const float* w4 = (const float*)d_in[12];
  const float* g4 = (const float*)d_in[13];
  const float* be4= (const float*)d_in[14];

  float* out = (float*)d_out;
  float* coor_out = out;                    // (32,128,3)
  float* f_out = out + BB*128*3;            // (32,128,256)

  char* ws = (char*)d_ws;
  size_t off = 0;
  auto alloc = [&](size_t bytes)->void*{ void* p = ws + off; off += (bytes + 255) & ~(size_t)255; return p; };

  // ---- persistent buffers ----
  float* f0     = (float*)alloc((size_t)BB*2048*8*4);
  int*   idx1   = (int*)  alloc((size_t)BB*2048*16*4);
  float* f1     = (float*)alloc((size_t)BB*2048*32*4);
  double* part  = (double*)alloc((size_t)BB*4*8*2*8);
  float* statsv = (float*)alloc((size_t)BB*4*2*4);
  int*   fidx0  = (int*)  alloc((size_t)BB*512*4);
  float* coorq1 = (float*)alloc((size_t)BB*512*3*4);
  float* fq1    = (float*)alloc((size_t)BB*512*32*4);
  int*   idx2   = (int*)  alloc((size_t)BB*512*16*4);
  float* f2     = (float*)alloc((size_t)BB*512*64*4);
  int*   idx3   = (int*)  alloc((size_t)BB*512*16*4);
  float* f3     = (float*)alloc((size_t)BB*512*64*4);
  int*   fidx1  = (int*)  alloc((size_t)BB*128*4);
  float* fq2    = (float*)alloc((size_t)BB*128*64*4);
  int*   idx4   = (int*)  alloc((size_t)BB*128*16*4);

  // ---- union scratch region (48 MB): kNN partials alias the A/B edge-conv buffers.
  char* U = (char*)alloc((size_t)48<<20);
  float* pd         = (float*)U;                              // max 32 MiB
  unsigned char* pi = (unsigned char*)(U + ((size_t)34<<20)); // max 8 MiB
  float* A  = (float*)U;                                      // max 16 MiB
  float* Bq = (float*)(U + ((size_t)20<<20));                 // max 4 MiB

  auto cdiv = [](int a, int b){ return (a+b-1)/b; };

  // stage 0: projection
  proj_kernel<<<cdiv(BB*2048,256),256,0,stream>>>(x, w_in, b_in, f0);

  // ---- stage 1: 2048 q x 2048 k ----
  knn_part_kernel<<<dim3(BB,8,8),256,0,stream>>>(x, x, 2048, 2048, pd, pi);
  knn_merge_kernel<<<cdiv(BB*2048,256),256,0,stream>>>(pd, pi, 2048, 8, idx1);
  gemv_kernel<8,32,false><<<cdiv(BB*2048*4,256),256,0,stream>>>(f0, w1, A, 2048);
  gemv_kernel<8,32,true ><<<cdiv(BB*2048*4,256),256,0,stream>>>(f0, w1, Bq, 2048);
  stats_kernel<32><<<dim3(BB,4,8),256,0,stream>>>(A, Bq, idx1, 2048, 2048, part);
  statsred_kernel<<<1,128,0,stream>>>(part, 8, 8.0*2048*16, statsv);
  final_kernel<32><<<dim3(cdiv(2048*32,256),BB),256,0,stream>>>(A, Bq, idx1, statsv, g1, be1, f1, 2048, 2048);

  // ---- fps 2048 -> 512 + gather ----
  fps_kernel<8><<<BB,256,0,stream>>>(x, 512, fidx0);
  gather_kernel<32><<<cdiv(BB*512,256),256,0,stream>>>(fidx0, x, f1, coorq1, fq1, 2048, 512);

  // ---- stage 2: 512 q x 2048 k ----
  knn_part_kernel<<<dim3(BB,2,8),256,0,stream>>>(coorq1, x, 512, 2048, pd, pi);
  knn_merge_kernel<<<cdiv(BB*512,256),256,0,stream>>>(pd, pi, 512, 8, idx2);
  gemv_kernel<32,64,false><<<cdiv(BB*2048*8,256),256,0,stream>>>(f1, w2, A, 2048);
  gemv_kernel<32,64,true ><<<cdiv(BB*512*8,256),256,0,stream>>>(fq1, w2, Bq, 512);
  stats_kernel<64><<<dim3(BB,4,8),256,0,stream>>>(A, Bq, idx2, 512, 2048, part);
  statsred_kernel<<<1,128,0,stream>>>(part, 8, 16.0*512*16, statsv);
  final_kernel<64><<<dim3(cdiv(512*64,256),BB),256,0,stream>>>(A, Bq, idx2, statsv, g2, be2, f2, 512, 2048);

  // ---- stage 3: 512 q x 512 k ----
  knn_part_kernel<<<dim3(BB,2,2),256,0,stream>>>(coorq1, coorq1, 512, 512, pd, pi);
  knn_merge_kernel<<<cdiv(BB*512,256),256,0,stream>>>(pd, pi, 512, 2, idx3);
  gemv_kernel<64,64,false><<<cdiv(BB*512*8,256),256,0,stream>>>(f2, w3, A, 512);
  gemv_kernel<64,64,true ><<<cdiv(BB*512*8,256),256,0,stream>>>(f2, w3, Bq, 512);
  stats_kernel<64><<<dim3(BB,4,8),256,0,stream>>>(A, Bq, idx3, 512, 512, part);
  statsred_kernel<<<1,128,0,stream>>>(part, 8, 16.0*512*16, statsv);
  final_kernel<64><<<dim3(cdiv(512*64,256),BB),256,0,stream>>>(A, Bq, idx3, statsv, g3, be3, f3, 512, 512);

  // ---- fps 512 -> 128 + gather (coords straight into d_out) ----
  fps_kernel<2><<<BB,256,0,stream>>>(coorq1, 128, fidx1);
  gather_kernel<64><<<cdiv(BB*128,256),256,0,stream>>>(fidx1, coorq1, f3, coor_out, fq2, 512, 128);

  // ---- stage 4: 128 q x 512 k ----
  knn_part_kernel<<<dim3(BB,1,2),256,0,stream>>>(coor_out, coorq1, 128, 512, pd, pi);
  knn_merge_kernel<<<cdiv(BB*128,256),256,0,stream>>>(pd, pi, 128, 2, idx4);
  gemv_kernel<64,256,false><<<cdiv(BB*512*32,256),256,0,stream>>>(f3, w4, A, 512);
  gemv_kernel<64,256,true ><<<cdiv(BB*128*32,256),256,0,stream>>>(fq2, w4, Bq, 128);
  stats_kernel<256><<<dim3(BB,4,8),256,0,stream>>>(A, Bq, idx4, 128, 512, part);
  statsred_kernel<<<1,128,0,stream>>>(part, 8, 64.0*128*16, statsv);
  final_kernel<256><<<dim3(cdiv(128*256,256),BB),256,0,stream>>>(A, Bq, idx4, statsv, g4, be4, f_out, 128, 512);
}